// Round 8
// baseline (288.540 us; speedup 1.0000x reference)
//
#include <hip/hip_runtime.h>
#include <math.h>

#define NH 49152
#define KI 1024
#define DD 32
#define HF 256

// float-index layout in ws
#define WS_PART  0                    // [0]=vrep [1]=vatt [2]=noise_sum [3]=n_noise(u32) [4]=sum(1-beta_a)
#define WS_SEG64 8                    // KI u64 packed (q_bits<<32 | NH-1-h)
#define WS_WT    2056                 // Wt[33][256] k-major (row 32 = Wb)
#define WS_A12   (WS_WT + 33*256)     // KI*12: d0..7, ca, qa, pad2
#define WS_H12   (WS_A12 + 12*KI)     // NH*12: d0..7, ch, q, bc, pad
#define WS_XA    (WS_H12 + 12*NH)     // KI*DD full alpha coords
#define WS_OX    (WS_XA + KI*DD)      // NH*DD

// pack W k-major (Wt[c][k]; row 32 = Wb) + zero seg64/parts
__global__ __launch_bounds__(256) void k_prep(const float* __restrict__ Wc,
                                              const float* __restrict__ Wb,
                                              float* __restrict__ ws) {
    const int i = blockIdx.x * 256 + threadIdx.x;
    if (i < 33 * 256) {
        const int c = i >> 8, k = i & 255;
        ws[WS_WT + i] = (c < 32) ? Wc[k * 32 + c] : Wb[k];
    }
    if (i < 512) *(float4*)(ws + WS_SEG64 + (size_t)i * 4) = make_float4(0.f, 0.f, 0.f, 0.f);
    if (i < 8) ws[WS_PART + i] = 0.0f;
}

// GEMM: both operands via VMEM only (no LDS / no s_load in loop -> no shared
// counter). Lane = (hit q 0..15, col-group cs 0..3); cols cs+4j, j=0..7 (+beta).
// x: private row stream (HBM, lines fully used). W: 33KB k-major, L1/L2-hot.
// W double-buffered ping-pong (zero v_movs); x prefetched 16-k ahead.
__global__ __launch_bounds__(256, 3) void k_gemm(
        const float* __restrict__ x, const float* __restrict__ bb,
        const float* __restrict__ bcrd, const int* __restrict__ yi,
        float* __restrict__ ws) {
    __shared__ float eps[64][40];
    const int t  = threadIdx.x;
    const int w  = t >> 6;
    const int l  = t & 63;
    const int q  = l >> 2;
    const int cs = l & 3;
    const int hl = w * 16 + q;
    const int h  = blockIdx.x * 64 + hl;
    const float* __restrict__ wt  = ws + WS_WT;
    const float* __restrict__ wp0 = wt + cs * 256;    // lane's col base (row cs+4j)
    const float* __restrict__ wtb = wt + 32 * 256;    // beta row
    const float* __restrict__ xp  = x + (size_t)h * HF;

    float acc[8];
    #pragma unroll
    for (int j = 0; j < 8; ++j) acc[j] = 0.0f;
    float accb = 0.0f;

    float4 wA[8], wB[8];
    float4 xc0, xc1, xc2, xc3, xn0, xn1, xn2, xn3;

    // prologue: x super-chunk 0 + W window 0
    xc0 = *(const float4*)(xp + 0);
    xc1 = *(const float4*)(xp + 4);
    xc2 = *(const float4*)(xp + 8);
    xc3 = *(const float4*)(xp + 12);
    #pragma unroll
    for (int j = 0; j < 8; ++j) wA[j] = *(const float4*)(wp0 + j * 1024);

#define WINDOW(CB, LB, XV, KN, GUARD) { \
        if (GUARD) { \
            _Pragma("unroll") \
            for (int j = 0; j < 8; ++j) \
                LB[j] = *(const float4*)(wp0 + j * 1024 + (KN)); \
        } \
        const float4 wb4 = *(const float4*)(wtb + (KN) - 4); \
        _Pragma("unroll") \
        for (int j = 0; j < 8; ++j) { \
            acc[j] = fmaf(XV.x, CB[j].x, acc[j]); \
            acc[j] = fmaf(XV.y, CB[j].y, acc[j]); \
            acc[j] = fmaf(XV.z, CB[j].z, acc[j]); \
            acc[j] = fmaf(XV.w, CB[j].w, acc[j]); \
        } \
        accb = fmaf(XV.x, wb4.x, accb); \
        accb = fmaf(XV.y, wb4.y, accb); \
        accb = fmaf(XV.z, wb4.z, accb); \
        accb = fmaf(XV.w, wb4.w, accb); \
    }

    for (int S = 0; S < 16; ++S) {
        const int kS = S * 16;
        if (S < 15) {                          // x prefetch: one full super-chunk ahead
            xn0 = *(const float4*)(xp + kS + 16);
            xn1 = *(const float4*)(xp + kS + 20);
            xn2 = *(const float4*)(xp + kS + 24);
            xn3 = *(const float4*)(xp + kS + 28);
        }
        WINDOW(wA, wB, xc0, kS + 4,  true);
        WINDOW(wB, wA, xc1, kS + 8,  true);
        WINDOW(wA, wB, xc2, kS + 12, true);
        WINDOW(wB, wA, xc3, kS + 16, (S < 15));
        xc0 = xn0; xc1 = xn1; xc2 = xn2; xc3 = xn3;
    }

    // epilogue: assemble per-hit rows via LDS (one-time)
    #pragma unroll
    for (int j = 0; j < 8; ++j) eps[hl][cs + 4 * j] = acc[j];
    if (cs == 0) eps[hl][32] = accb;
    __syncthreads();

    const int h2l = t >> 2;
    const int dg  = t & 3;
    const int hh  = blockIdx.x * 64 + h2l;
    const float4 ea  = *(const float4*)(&eps[h2l][dg * 8]);
    const float4 eb  = *(const float4*)(&eps[h2l][dg * 8 + 4]);
    const float4 ba  = *(const float4*)(bcrd + dg * 8);
    const float4 bb4 = *(const float4*)(bcrd + dg * 8 + 4);
    const float4 o0 = {ea.x + ba.x, ea.y + ba.y, ea.z + ba.z, ea.w + ba.w};
    const float4 o1 = {eb.x + bb4.x, eb.y + bb4.y, eb.z + bb4.z, eb.w + bb4.w};
    *(float4*)(ws + WS_OX + (size_t)hh * DD + dg * 8)     = o0;
    *(float4*)(ws + WS_OX + (size_t)hh * DD + dg * 8 + 4) = o1;

    float nb = 0.0f; unsigned cnt = 0u;
    if (dg == 0) {   // this thread owns hit hh's record (dims 0..7 = its o0,o1)
        const float s8 = o0.x*o0.x + o0.y*o0.y + o0.z*o0.z + o0.w*o0.w
                       + o1.x*o1.x + o1.y*o1.y + o1.z*o1.z + o1.w*o1.w;
        float* hr = ws + WS_H12 + (size_t)hh * 12;
        *(float4*)(hr)     = o0;
        *(float4*)(hr + 4) = o1;
        hr[8] = 0.5f * s8;
        const float z    = eps[h2l][32] + bb[0];
        const float beta = 1.0f / (1.0f + expf(-z));
        const float bcv  = fminf(fmaxf(beta, 1e-4f), 0.9999f);
        const float at   = atanhf(bcv);
        hr[9]  = at * at + 0.5f;
        hr[10] = bcv;
        const int y = yi[hh];
        if (y < 0) { nb = bcv; cnt = 1u; }
    }
    nb += __shfl_down(nb, 32);  cnt += __shfl_down(cnt, 32);
    nb += __shfl_down(nb, 16);  cnt += __shfl_down(cnt, 16);
    nb += __shfl_down(nb, 8);   cnt += __shfl_down(cnt, 8);
    nb += __shfl_down(nb, 4);   cnt += __shfl_down(cnt, 4);
    if (l == 0) {
        atomicAdd(ws + WS_PART + 2, nb);
        atomicAdd((unsigned int*)(ws + WS_PART + 3), cnt);
    }
}

// fused segment argmax: pack (q_bits, NH-1-h) -> one u64 atomicMax.
__global__ __launch_bounds__(256) void k_segmax(const int* __restrict__ eh, const int* __restrict__ ei,
                                                int E, const float* __restrict__ h12,
                                                unsigned long long* __restrict__ seg) {
    int e = blockIdx.x * 256 + threadIdx.x;
    if (e < E) {
        int h = eh[e];
        float q = h12[(size_t)h * 12 + 9];
        unsigned long long pk = ((unsigned long long)__float_as_uint(q) << 32)
                              | (unsigned)(NH - 1 - h);
        atomicMax(seg + ei[e], pk);
    }
}

__global__ __launch_bounds__(256) void k_gather(float* __restrict__ ws) {
    const int k = blockIdx.x * 256 + threadIdx.x;
    unsigned long long pk = ((const unsigned long long*)(ws + WS_SEG64))[k];
    int a = NH - 1 - (int)(unsigned)(pk & 0xffffffffu);
    a = max(0, min(a, NH - 1));
    float4 v0, v1;
    float s8 = 0.0f;
    #pragma unroll
    for (int d0 = 0; d0 < DD; d0 += 4) {
        float4 v = *(const float4*)(ws + WS_OX + (size_t)a * DD + d0);
        *(float4*)(ws + WS_XA + (size_t)k * DD + d0) = v;
        if (d0 == 0) { v0 = v; s8 += v.x*v.x + v.y*v.y + v.z*v.z + v.w*v.w; }
        if (d0 == 4) { v1 = v; s8 += v.x*v.x + v.y*v.y + v.z*v.z + v.w*v.w; }
    }
    *(float4*)(ws + WS_A12 + (size_t)k * 12)     = v0;
    *(float4*)(ws + WS_A12 + (size_t)k * 12 + 4) = v1;
    ws[WS_A12 + (size_t)k * 12 + 8] = 0.5f * (s8 - 1.0f);                    // ca
    ws[WS_A12 + (size_t)k * 12 + 9] = ws[WS_H12 + (size_t)a * 12 + 9];       // qa
    float omba = 1.0f - ws[WS_H12 + (size_t)a * 12 + 10];
    for (int off = 32; off > 0; off >>= 1) omba += __shfl_down(omba, off);
    if ((threadIdx.x & 63) == 0) atomicAdd(ws + WS_PART + 4, omba);
}

__global__ __launch_bounds__(256) void k_att(const int* __restrict__ eh, const int* __restrict__ ei,
                                             int E, float* __restrict__ ws) {
    const int t = threadIdx.x;
    const int e = blockIdx.x * 256 + t;
    float c = 0.0f;
    if (e < E) {
        const int h = eh[e], k = ei[e];
        const float* a = ws + WS_OX + (size_t)h * DD;
        const float* b = ws + WS_XA + (size_t)k * DD;
        float d2 = 0.0f;
        #pragma unroll
        for (int d0 = 0; d0 < DD; d0 += 4) {
            float4 av = *(const float4*)(a + d0);
            float4 bv = *(const float4*)(b + d0);
            float dx = av.x - bv.x; d2 = fmaf(dx, dx, d2);
            float dy = av.y - bv.y; d2 = fmaf(dy, dy, d2);
            float dz = av.z - bv.z; d2 = fmaf(dz, dz, d2);
            float dw = av.w - bv.w; d2 = fmaf(dw, dw, d2);
        }
        c = ws[WS_H12 + (size_t)h * 12 + 9] * ws[WS_A12 + (size_t)k * 12 + 9] * d2;
    }
    for (int off = 32; off > 0; off >>= 1) c += __shfl_down(c, off);
    __shared__ float red[4];
    if ((t & 63) == 0) red[t >> 6] = c;
    __syncthreads();
    if (t == 0) atomicAdd(ws + WS_PART + 1, red[0] + red[1] + red[2] + red[3]);
}

// v_rep: 512 hits x 128 alphas per block; alpha records staged in LDS.
// Exact 8-dim lower-bound filter.
__global__ __launch_bounds__(256, 4) void k_rep(const int* __restrict__ yi,
        const float* __restrict__ a12, const float* __restrict__ h12,
        const float* __restrict__ ox, const float* __restrict__ xa,
        float* __restrict__ part) {
    __shared__ float al[128 * 12];
    const int t  = threadIdx.x;
    const int bh = blockIdx.x % 96;
    const int bk = blockIdx.x / 96;
    const int k0 = bk * 128;

    for (int i = t; i < 128 * 12; i += 256)
        al[i] = a12[(size_t)k0 * 12 + i];
    __syncthreads();

    const int h1 = bh * 512 + t;
    const int h2 = h1 + 256;
    const float4 p0  = *(const float4*)(h12 + (size_t)h1 * 12);
    const float4 p1  = *(const float4*)(h12 + (size_t)h1 * 12 + 4);
    const float2 cq1 = *(const float2*)(h12 + (size_t)h1 * 12 + 8);
    const float4 s0  = *(const float4*)(h12 + (size_t)h2 * 12);
    const float4 s1  = *(const float4*)(h12 + (size_t)h2 * 12 + 4);
    const float2 cq2 = *(const float2*)(h12 + (size_t)h2 * 12 + 8);
    const int yh1 = yi[h1], yh2 = yi[h2];
    float loc = 0.0f;

    #pragma unroll 4
    for (int r = 0; r < 128; ++r) {
        const float4 b0  = *(const float4*)(al + r * 12);
        const float4 b1  = *(const float4*)(al + r * 12 + 4);
        const float2 bcq = *(const float2*)(al + r * 12 + 8);
        float acc1 = -cq1.x - bcq.x;
        acc1 = fmaf(p0.x, b0.x, acc1);
        acc1 = fmaf(p0.y, b0.y, acc1);
        acc1 = fmaf(p0.z, b0.z, acc1);
        acc1 = fmaf(p0.w, b0.w, acc1);
        acc1 = fmaf(p1.x, b1.x, acc1);
        acc1 = fmaf(p1.y, b1.y, acc1);
        acc1 = fmaf(p1.z, b1.z, acc1);
        acc1 = fmaf(p1.w, b1.w, acc1);
        float acc2 = -cq2.x - bcq.x;
        acc2 = fmaf(s0.x, b0.x, acc2);
        acc2 = fmaf(s0.y, b0.y, acc2);
        acc2 = fmaf(s0.z, b0.z, acc2);
        acc2 = fmaf(s0.w, b0.w, acc2);
        acc2 = fmaf(s1.x, b1.x, acc2);
        acc2 = fmaf(s1.y, b1.y, acc2);
        acc2 = fmaf(s1.z, b1.z, acc2);
        acc2 = fmaf(s1.w, b1.w, acc2);
        if (acc1 > 0.0f) {          // rare: d2 over first 8 dims < 1
            const int kg = k0 + r;
            if (yh1 != kg) {
                float d2 = 1.0f - 2.0f * acc1;
                const float* hp  = ox + (size_t)h1 * DD;
                const float* apf = xa + (size_t)kg * DD;
                #pragma unroll
                for (int d = 8; d < DD; d += 4) {
                    float4 av = *(const float4*)(hp + d);
                    float4 bv = *(const float4*)(apf + d);
                    float dx = av.x - bv.x; d2 = fmaf(dx, dx, d2);
                    float dy = av.y - bv.y; d2 = fmaf(dy, dy, d2);
                    float dz = av.z - bv.z; d2 = fmaf(dz, dz, d2);
                    float dw = av.w - bv.w; d2 = fmaf(dw, dw, d2);
                }
                float dist = sqrtf(fmaxf(d2, 0.0f) + 1e-12f);
                float hin  = 1.0f - dist;
                if (hin > 0.0f) loc += cq1.y * bcq.y * hin;
            }
        }
        if (acc2 > 0.0f) {
            const int kg = k0 + r;
            if (yh2 != kg) {
                float d2 = 1.0f - 2.0f * acc2;
                const float* hp  = ox + (size_t)h2 * DD;
                const float* apf = xa + (size_t)kg * DD;
                #pragma unroll
                for (int d = 8; d < DD; d += 4) {
                    float4 av = *(const float4*)(hp + d);
                    float4 bv = *(const float4*)(apf + d);
                    float dx = av.x - bv.x; d2 = fmaf(dx, dx, d2);
                    float dy = av.y - bv.y; d2 = fmaf(dy, dy, d2);
                    float dz = av.z - bv.z; d2 = fmaf(dz, dz, d2);
                    float dw = av.w - bv.w; d2 = fmaf(dw, dw, d2);
                }
                float dist = sqrtf(fmaxf(d2, 0.0f) + 1e-12f);
                float hin  = 1.0f - dist;
                if (hin > 0.0f) loc += cq2.y * bcq.y * hin;
            }
        }
    }
    for (int off = 32; off > 0; off >>= 1) loc += __shfl_down(loc, off);
    __shared__ float red[4];
    if ((t & 63) == 0) red[t >> 6] = loc;
    __syncthreads();
    if (t == 0) atomicAdd(part + 0, red[0] + red[1] + red[2] + red[3]);
}

__global__ void k_final(const float* __restrict__ temp, float* __restrict__ ws,
                        float* __restrict__ out) {
    float vrep  = ws[WS_PART + 0];
    float vatt  = ws[WS_PART + 1];
    float nsum  = ws[WS_PART + 2];
    unsigned nn = *(const unsigned int*)(ws + WS_PART + 3);
    float somba = ws[WS_PART + 4];
    float lb = somba * (1.0f / (float)KI) + nsum / (float)(nn < 1u ? 1u : nn);
    float lv = (vatt + vrep) / (float)NH;
    float tv = temp[0];
    out[0] = (lb + lv) * expf(-tv) + tv;
}

extern "C" void kernel_launch(void* const* d_in, const int* in_sizes, int n_in,
                              void* d_out, int out_size, void* d_ws, size_t ws_size,
                              hipStream_t stream) {
    const float* x    = (const float*)d_in[0];
    const float* Wb   = (const float*)d_in[1];
    const float* bb   = (const float*)d_in[2];
    const float* Wc   = (const float*)d_in[3];
    const float* bcrd = (const float*)d_in[4];
    const float* temp = (const float*)d_in[5];
    const int*   yi   = (const int*)d_in[6];
    const int*   ep   = (const int*)d_in[8];
    const int E = in_sizes[8] / 2;
    const int* eh = ep;
    const int* ei = ep + E;
    float* ws  = (float*)d_ws;
    float* out = (float*)d_out;

    k_prep<<<34, 256, 0, stream>>>(Wc, Wb, ws);
    k_gemm<<<NH / 64, 256, 0, stream>>>(x, bb, bcrd, yi, ws);
    const int eb = (E + 255) / 256;
    k_segmax<<<eb, 256, 0, stream>>>(eh, ei, E, ws + WS_H12,
                                     (unsigned long long*)(ws + WS_SEG64));
    k_gather<<<KI / 256, 256, 0, stream>>>(ws);
    k_att<<<eb, 256, 0, stream>>>(eh, ei, E, ws);
    k_rep<<<96 * 8, 256, 0, stream>>>(yi, ws + WS_A12, ws + WS_H12,
                                      ws + WS_OX, ws + WS_XA, ws);
    k_final<<<1, 1, 0, stream>>>(temp, ws, out);
}

// Round 9
// 108.104 us; speedup vs baseline: 2.6691x; 2.6691x over previous
//
#include <hip/hip_runtime.h>
#include <math.h>

#define NH 49152
#define KI 1024
#define DD 32
#define HF 256

// float-index layout in ws
#define WS_PART  0                    // [0]=vrep [1]=vatt [2]=noise_sum [3]=n_noise(u32) [4]=sum(1-beta_a)
#define WS_SEG64 8                    // KI u64 packed (q_bits<<32 | NH-1-h)
#define WS_WT    2056                 // W3[4][64][4][8] (8192) + wb[256] = 8448
#define WS_A12   (WS_WT + 8448)      // KI*12: d0..7, ca, qa, pad2
#define WS_H12   (WS_A12 + 12*KI)     // NH*12: d0..7, ch, q, bc, pad
#define WS_XA    (WS_H12 + 12*NH)     // KI*DD full alpha coords
#define WS_OX    (WS_XA + KI*DD)      // NH*DD

// pack W window-blocked: W3[w][win][k][j] = Wc[(win*4+k)*32 + w*8+j]; wb[k]=Wb[k]
__global__ __launch_bounds__(256) void k_prep(const float* __restrict__ Wc,
                                              const float* __restrict__ Wb,
                                              float* __restrict__ ws) {
    const int i = blockIdx.x * 256 + threadIdx.x;
    if (i < 8192) {
        const int w = i >> 11, r = i & 2047;
        const int win = r >> 5, kj = r & 31;
        const int kk = kj >> 3, j = kj & 7;
        ws[WS_WT + i] = Wc[(size_t)(win * 4 + kk) * 32 + w * 8 + j];
    } else if (i < 8448) {
        ws[WS_WT + i] = Wb[i - 8192];
    }
    if (i < 512) *(float4*)(ws + WS_SEG64 + (size_t)i * 4) = make_float4(0.f, 0.f, 0.f, 0.f);
    if (i < 8) ws[WS_PART + i] = 0.0f;
}

// GEMM: x streamed per-lane from global (vmcnt, 4-deep pipeline); W via
// wave-uniform s_load from packed W3 (lgkmcnt, SGPR broadcast operands);
// NO LDS and no counter sharing in the loop. lane = hit, wave = col octet.
__global__ __launch_bounds__(256, 3) void k_gemm(
        const float* __restrict__ x, const float* __restrict__ bb,
        const float* __restrict__ bcrd, const int* __restrict__ yi,
        float* __restrict__ ws) {
    const int t = threadIdx.x;
    const int w = __builtin_amdgcn_readfirstlane(t >> 6);  // col octet (uniform)
    const int l = t & 63;                                  // lane = hit
    const int h = blockIdx.x * 64 + l;
    const float* __restrict__ wt3 = ws + WS_WT + w * 2048; // this wave's W blocks
    const float* __restrict__ wtb = ws + WS_WT + 8192;     // beta column
    const float* __restrict__ xp  = x + (size_t)h * HF;

    float acc[8];
    #pragma unroll
    for (int j = 0; j < 8; ++j) acc[j] = 0.0f;
    float accb = 0.0f;

#define COMPUTE(XV, WIN) { \
        const float* wp = wt3 + (WIN) * 32; \
        _Pragma("unroll") \
        for (int j = 0; j < 8; ++j) { \
            acc[j] = fmaf(XV.x, wp[j],      acc[j]); \
            acc[j] = fmaf(XV.y, wp[8 + j],  acc[j]); \
            acc[j] = fmaf(XV.z, wp[16 + j], acc[j]); \
            acc[j] = fmaf(XV.w, wp[24 + j], acc[j]); \
        } \
        if (w == 3) { \
            const float* wpb = wtb + (WIN) * 4; \
            accb = fmaf(XV.x, wpb[0], accb); \
            accb = fmaf(XV.y, wpb[1], accb); \
            accb = fmaf(XV.z, wpb[2], accb); \
            accb = fmaf(XV.w, wpb[3], accb); \
        } \
    }

    // 4-deep x pipeline over 64 windows of 4 k each
    float4 x0 = *(const float4*)(xp + 0);
    float4 x1 = *(const float4*)(xp + 4);
    float4 x2 = *(const float4*)(xp + 8);
    float4 x3 = *(const float4*)(xp + 12);
    for (int S4 = 0; S4 < 15; ++S4) {
        const int wb4 = S4 * 4;
        COMPUTE(x0, wb4 + 0);  x0 = *(const float4*)(xp + wb4 * 4 + 16);
        COMPUTE(x1, wb4 + 1);  x1 = *(const float4*)(xp + wb4 * 4 + 20);
        COMPUTE(x2, wb4 + 2);  x2 = *(const float4*)(xp + wb4 * 4 + 24);
        COMPUTE(x3, wb4 + 3);  x3 = *(const float4*)(xp + wb4 * 4 + 28);
    }
    COMPUTE(x0, 60);
    COMPUTE(x1, 61);
    COMPUTE(x2, 62);
    COMPUTE(x3, 63);

    // epilogue: lane holds its hit's full col-octet -> direct stores
    const float4 ba0 = *(const float4*)(bcrd + w * 8);
    const float4 ba1 = *(const float4*)(bcrd + w * 8 + 4);
    const float4 o0 = {acc[0] + ba0.x, acc[1] + ba0.y, acc[2] + ba0.z, acc[3] + ba0.w};
    const float4 o1 = {acc[4] + ba1.x, acc[5] + ba1.y, acc[6] + ba1.z, acc[7] + ba1.w};
    *(float4*)(ws + WS_OX + (size_t)h * DD + w * 8)     = o0;
    *(float4*)(ws + WS_OX + (size_t)h * DD + w * 8 + 4) = o1;

    if (w == 0) {   // cols 0..7: filter record dims + half-norm
        const float s8 = o0.x*o0.x + o0.y*o0.y + o0.z*o0.z + o0.w*o0.w
                       + o1.x*o1.x + o1.y*o1.y + o1.z*o1.z + o1.w*o1.w;
        float* hr = ws + WS_H12 + (size_t)h * 12;
        *(float4*)(hr)     = o0;
        *(float4*)(hr + 4) = o1;
        hr[8] = 0.5f * s8;
    }
    if (w == 3) {   // beta path + noise sums
        const float z    = accb + bb[0];
        const float beta = 1.0f / (1.0f + expf(-z));
        const float bcv  = fminf(fmaxf(beta, 1e-4f), 0.9999f);
        const float at   = atanhf(bcv);
        float* hr = ws + WS_H12 + (size_t)h * 12;
        hr[9]  = at * at + 0.5f;
        hr[10] = bcv;
        const int y = yi[h];
        float    nb  = (y < 0) ? bcv : 0.0f;
        unsigned cnt = (y < 0) ? 1u : 0u;
        for (int off = 32; off > 0; off >>= 1) {
            nb  += __shfl_down(nb, off);
            cnt += __shfl_down(cnt, off);
        }
        if (l == 0) {
            atomicAdd(ws + WS_PART + 2, nb);
            atomicAdd((unsigned int*)(ws + WS_PART + 3), cnt);
        }
    }
}

// fused segment argmax: pack (q_bits, NH-1-h) -> one u64 atomicMax.
__global__ __launch_bounds__(256) void k_segmax(const int* __restrict__ eh, const int* __restrict__ ei,
                                                int E, const float* __restrict__ h12,
                                                unsigned long long* __restrict__ seg) {
    int e = blockIdx.x * 256 + threadIdx.x;
    if (e < E) {
        int h = eh[e];
        float q = h12[(size_t)h * 12 + 9];
        unsigned long long pk = ((unsigned long long)__float_as_uint(q) << 32)
                              | (unsigned)(NH - 1 - h);
        atomicMax(seg + ei[e], pk);
    }
}

__global__ __launch_bounds__(256) void k_gather(float* __restrict__ ws) {
    const int k = blockIdx.x * 256 + threadIdx.x;
    unsigned long long pk = ((const unsigned long long*)(ws + WS_SEG64))[k];
    int a = NH - 1 - (int)(unsigned)(pk & 0xffffffffu);
    a = max(0, min(a, NH - 1));
    float4 v0, v1;
    float s8 = 0.0f;
    #pragma unroll
    for (int d0 = 0; d0 < DD; d0 += 4) {
        float4 v = *(const float4*)(ws + WS_OX + (size_t)a * DD + d0);
        *(float4*)(ws + WS_XA + (size_t)k * DD + d0) = v;
        if (d0 == 0) { v0 = v; s8 += v.x*v.x + v.y*v.y + v.z*v.z + v.w*v.w; }
        if (d0 == 4) { v1 = v; s8 += v.x*v.x + v.y*v.y + v.z*v.z + v.w*v.w; }
    }
    *(float4*)(ws + WS_A12 + (size_t)k * 12)     = v0;
    *(float4*)(ws + WS_A12 + (size_t)k * 12 + 4) = v1;
    ws[WS_A12 + (size_t)k * 12 + 8] = 0.5f * (s8 - 1.0f);                    // ca
    ws[WS_A12 + (size_t)k * 12 + 9] = ws[WS_H12 + (size_t)a * 12 + 9];       // qa
    float omba = 1.0f - ws[WS_H12 + (size_t)a * 12 + 10];
    for (int off = 32; off > 0; off >>= 1) omba += __shfl_down(omba, off);
    if ((threadIdx.x & 63) == 0) atomicAdd(ws + WS_PART + 4, omba);
}

__global__ __launch_bounds__(256) void k_att(const int* __restrict__ eh, const int* __restrict__ ei,
                                             int E, float* __restrict__ ws) {
    const int t = threadIdx.x;
    const int e = blockIdx.x * 256 + t;
    float c = 0.0f;
    if (e < E) {
        const int h = eh[e], k = ei[e];
        const float* a = ws + WS_OX + (size_t)h * DD;
        const float* b = ws + WS_XA + (size_t)k * DD;
        float d2 = 0.0f;
        #pragma unroll
        for (int d0 = 0; d0 < DD; d0 += 4) {
            float4 av = *(const float4*)(a + d0);
            float4 bv = *(const float4*)(b + d0);
            float dx = av.x - bv.x; d2 = fmaf(dx, dx, d2);
            float dy = av.y - bv.y; d2 = fmaf(dy, dy, d2);
            float dz = av.z - bv.z; d2 = fmaf(dz, dz, d2);
            float dw = av.w - bv.w; d2 = fmaf(dw, dw, d2);
        }
        c = ws[WS_H12 + (size_t)h * 12 + 9] * ws[WS_A12 + (size_t)k * 12 + 9] * d2;
    }
    for (int off = 32; off > 0; off >>= 1) c += __shfl_down(c, off);
    __shared__ float red[4];
    if ((t & 63) == 0) red[t >> 6] = c;
    __syncthreads();
    if (t == 0) atomicAdd(ws + WS_PART + 1, red[0] + red[1] + red[2] + red[3]);
}

// v_rep: 512 hits x 128 alphas per block; alpha records staged in LDS.
// Exact 8-dim lower-bound filter.
__global__ __launch_bounds__(256, 4) void k_rep(const int* __restrict__ yi,
        const float* __restrict__ a12, const float* __restrict__ h12,
        const float* __restrict__ ox, const float* __restrict__ xa,
        float* __restrict__ part) {
    __shared__ float al[128 * 12];
    const int t  = threadIdx.x;
    const int bh = blockIdx.x % 96;
    const int bk = blockIdx.x / 96;
    const int k0 = bk * 128;

    for (int i = t; i < 128 * 12; i += 256)
        al[i] = a12[(size_t)k0 * 12 + i];
    __syncthreads();

    const int h1 = bh * 512 + t;
    const int h2 = h1 + 256;
    const float4 p0  = *(const float4*)(h12 + (size_t)h1 * 12);
    const float4 p1  = *(const float4*)(h12 + (size_t)h1 * 12 + 4);
    const float2 cq1 = *(const float2*)(h12 + (size_t)h1 * 12 + 8);
    const float4 s0  = *(const float4*)(h12 + (size_t)h2 * 12);
    const float4 s1  = *(const float4*)(h12 + (size_t)h2 * 12 + 4);
    const float2 cq2 = *(const float2*)(h12 + (size_t)h2 * 12 + 8);
    const int yh1 = yi[h1], yh2 = yi[h2];
    float loc = 0.0f;

    #pragma unroll 4
    for (int r = 0; r < 128; ++r) {
        const float4 b0  = *(const float4*)(al + r * 12);
        const float4 b1  = *(const float4*)(al + r * 12 + 4);
        const float2 bcq = *(const float2*)(al + r * 12 + 8);
        float acc1 = -cq1.x - bcq.x;
        acc1 = fmaf(p0.x, b0.x, acc1);
        acc1 = fmaf(p0.y, b0.y, acc1);
        acc1 = fmaf(p0.z, b0.z, acc1);
        acc1 = fmaf(p0.w, b0.w, acc1);
        acc1 = fmaf(p1.x, b1.x, acc1);
        acc1 = fmaf(p1.y, b1.y, acc1);
        acc1 = fmaf(p1.z, b1.z, acc1);
        acc1 = fmaf(p1.w, b1.w, acc1);
        float acc2 = -cq2.x - bcq.x;
        acc2 = fmaf(s0.x, b0.x, acc2);
        acc2 = fmaf(s0.y, b0.y, acc2);
        acc2 = fmaf(s0.z, b0.z, acc2);
        acc2 = fmaf(s0.w, b0.w, acc2);
        acc2 = fmaf(s1.x, b1.x, acc2);
        acc2 = fmaf(s1.y, b1.y, acc2);
        acc2 = fmaf(s1.z, b1.z, acc2);
        acc2 = fmaf(s1.w, b1.w, acc2);
        if (acc1 > 0.0f) {          // rare: d2 over first 8 dims < 1
            const int kg = k0 + r;
            if (yh1 != kg) {
                float d2 = 1.0f - 2.0f * acc1;
                const float* hp  = ox + (size_t)h1 * DD;
                const float* apf = xa + (size_t)kg * DD;
                #pragma unroll
                for (int d = 8; d < DD; d += 4) {
                    float4 av = *(const float4*)(hp + d);
                    float4 bv = *(const float4*)(apf + d);
                    float dx = av.x - bv.x; d2 = fmaf(dx, dx, d2);
                    float dy = av.y - bv.y; d2 = fmaf(dy, dy, d2);
                    float dz = av.z - bv.z; d2 = fmaf(dz, dz, d2);
                    float dw = av.w - bv.w; d2 = fmaf(dw, dw, d2);
                }
                float dist = sqrtf(fmaxf(d2, 0.0f) + 1e-12f);
                float hin  = 1.0f - dist;
                if (hin > 0.0f) loc += cq1.y * bcq.y * hin;
            }
        }
        if (acc2 > 0.0f) {
            const int kg = k0 + r;
            if (yh2 != kg) {
                float d2 = 1.0f - 2.0f * acc2;
                const float* hp  = ox + (size_t)h2 * DD;
                const float* apf = xa + (size_t)kg * DD;
                #pragma unroll
                for (int d = 8; d < DD; d += 4) {
                    float4 av = *(const float4*)(hp + d);
                    float4 bv = *(const float4*)(apf + d);
                    float dx = av.x - bv.x; d2 = fmaf(dx, dx, d2);
                    float dy = av.y - bv.y; d2 = fmaf(dy, dy, d2);
                    float dz = av.z - bv.z; d2 = fmaf(dz, dz, d2);
                    float dw = av.w - bv.w; d2 = fmaf(dw, dw, d2);
                }
                float dist = sqrtf(fmaxf(d2, 0.0f) + 1e-12f);
                float hin  = 1.0f - dist;
                if (hin > 0.0f) loc += cq2.y * bcq.y * hin;
            }
        }
    }
    for (int off = 32; off > 0; off >>= 1) loc += __shfl_down(loc, off);
    __shared__ float red[4];
    if ((t & 63) == 0) red[t >> 6] = loc;
    __syncthreads();
    if (t == 0) atomicAdd(part + 0, red[0] + red[1] + red[2] + red[3]);
}

__global__ void k_final(const float* __restrict__ temp, float* __restrict__ ws,
                        float* __restrict__ out) {
    float vrep  = ws[WS_PART + 0];
    float vatt  = ws[WS_PART + 1];
    float nsum  = ws[WS_PART + 2];
    unsigned nn = *(const unsigned int*)(ws + WS_PART + 3);
    float somba = ws[WS_PART + 4];
    float lb = somba * (1.0f / (float)KI) + nsum / (float)(nn < 1u ? 1u : nn);
    float lv = (vatt + vrep) / (float)NH;
    float tv = temp[0];
    out[0] = (lb + lv) * expf(-tv) + tv;
}

extern "C" void kernel_launch(void* const* d_in, const int* in_sizes, int n_in,
                              void* d_out, int out_size, void* d_ws, size_t ws_size,
                              hipStream_t stream) {
    const float* x    = (const float*)d_in[0];
    const float* Wb   = (const float*)d_in[1];
    const float* bb   = (const float*)d_in[2];
    const float* Wc   = (const float*)d_in[3];
    const float* bcrd = (const float*)d_in[4];
    const float* temp = (const float*)d_in[5];
    const int*   yi   = (const int*)d_in[6];
    const int*   ep   = (const int*)d_in[8];
    const int E = in_sizes[8] / 2;
    const int* eh = ep;
    const int* ei = ep + E;
    float* ws  = (float*)d_ws;
    float* out = (float*)d_out;

    k_prep<<<34, 256, 0, stream>>>(Wc, Wb, ws);
    k_gemm<<<NH / 64, 256, 0, stream>>>(x, bb, bcrd, yi, ws);
    const int eb = (E + 255) / 256;
    k_segmax<<<eb, 256, 0, stream>>>(eh, ei, E, ws + WS_H12,
                                     (unsigned long long*)(ws + WS_SEG64));
    k_gather<<<KI / 256, 256, 0, stream>>>(ws);
    k_att<<<eb, 256, 0, stream>>>(eh, ei, E, ws);
    k_rep<<<96 * 8, 256, 0, stream>>>(yi, ws + WS_A12, ws + WS_H12,
                                      ws + WS_OX, ws + WS_XA, ws);
    k_final<<<1, 1, 0, stream>>>(temp, ws, out);
}